// Round 7
// baseline (5527.803 us; speedup 1.0000x reference)
//
#include <hip/hip_runtime.h>

typedef _Float16 f16x8 __attribute__((ext_vector_type(8)));
typedef float    f32x4 __attribute__((ext_vector_type(4)));

#define DEVINL __device__ __forceinline__

namespace {
constexpr int Tt = 256, Ff = 128, Hh = 256, Uu = 512, OUTo = 128;
constexpr int NCLUST = 32;               // 512 / 16 row-groups
constexpr int CBLK = 8;                  // blocks per cluster
constexpr int NPAIR = 16;                // clusters handled pairwise per block column
constexpr int NSLOT = 68;                // frags per (cb, wave): 12 W1 + 16 W2 + 32 heads + 8 Wout
constexpr int NFRAG = CBLK * 4 * NSLOT;  // 2176 fragments
constexpr size_t WFRAG_BYTES = (size_t)NFRAG * 1024;
constexpr size_t ACT_OFF = WFRAG_BYTES;
constexpr size_t ACT_STRIDE = 40960;     // z1 16K | z2 16K | h 8K (+pad)
constexpr size_t CNT_OFF = ACT_OFF + (size_t)NCLUST * ACT_STRIDE;
constexpr size_t CNT_BYTES = (size_t)NCLUST * 8 * 4;
}

// ---- weight prep: f32 row-major -> per-(cb,wave) fp16 MFMA fragment banks ----
__global__ void prep_weights(const float* __restrict__ W1, const float* __restrict__ W2,
                             const float* __restrict__ Wff1, const float* __restrict__ Wff2,
                             const float* __restrict__ Wta, const float* __restrict__ Wtb,
                             const float* __restrict__ Wout, _Float16* __restrict__ ws)
{
    int o = blockIdx.x * blockDim.x + threadIdx.x;
    if (o >= NFRAG * 512) return;
    int j = o & 7, l = (o >> 3) & 63, r = o >> 9;
    int slot = r % NSLOT, bw = r / NSLOT;
    int w = bw & 3, cb = bw >> 2;
    int k_in = ((l >> 4) << 3) + j, lc = l & 15;
    float v;
    if (slot < 12) {
        int kt = slot;
        v = W1[(kt * 32 + k_in) * Uu + cb * 64 + w * 16 + lc];
    } else if (slot < 28) {
        int kt = slot - 12;
        v = W2[(kt * 32 + k_in) * Uu + cb * 64 + w * 16 + lc];
    } else if (slot < 60) {
        int s = slot - 28, hpL = s >> 4, kt = s & 15;
        int head = (w & 1) * 2 + hpL;
        const float* W = (head == 0) ? Wff1 : (head == 1) ? Wff2 : (head == 2) ? Wta : Wtb;
        v = W[(kt * 32 + k_in) * Hh + cb * 32 + (w >> 1) * 16 + lc];
    } else {
        int kt = slot - 60;
        v = Wout[(kt * 32 + k_in) * OUTo + cb * 16 + lc];
    }
    ws[o] = (_Float16)v;
}

DEVINL float fast_tanh(float v) {
    float e = __expf(2.0f * v);
    return 1.0f - 2.0f / (e + 1.0f);
}
DEVINL float fast_sigmoid(float v) { return 1.0f / (1.0f + __expf(-v)); }
DEVINL float lecun_act(float v)    { return 1.7159f * fast_tanh(0.666f * v); }

// ---- wide MALL-coherent (sc0 sc1) accessors ----
DEVINL void stg16_sys(_Float16* p, f16x8 v) {
    asm volatile("global_store_dwordx4 %0, %1, off sc0 sc1" :: "v"(p), "v"(v) : "memory");
}

#define LD8_FRAGS(d, base) \
    asm volatile( \
        "global_load_dwordx4 %0, %8, off sc0 sc1\n\t" \
        "global_load_dwordx4 %1, %8, off offset:64 sc0 sc1\n\t" \
        "global_load_dwordx4 %2, %8, off offset:128 sc0 sc1\n\t" \
        "global_load_dwordx4 %3, %8, off offset:192 sc0 sc1\n\t" \
        "global_load_dwordx4 %4, %8, off offset:256 sc0 sc1\n\t" \
        "global_load_dwordx4 %5, %8, off offset:320 sc0 sc1\n\t" \
        "global_load_dwordx4 %6, %8, off offset:384 sc0 sc1\n\t" \
        "global_load_dwordx4 %7, %8, off offset:448 sc0 sc1\n\t" \
        "s_waitcnt vmcnt(0)" \
        : "=&v"(d[0]), "=&v"(d[1]), "=&v"(d[2]), "=&v"(d[3]), \
          "=&v"(d[4]), "=&v"(d[5]), "=&v"(d[6]), "=&v"(d[7]) \
        : "v"(base) : "memory")

#define LD16_FRAGS(d, base) \
    asm volatile( \
        "global_load_dwordx4 %0, %16, off sc0 sc1\n\t" \
        "global_load_dwordx4 %1, %16, off offset:64 sc0 sc1\n\t" \
        "global_load_dwordx4 %2, %16, off offset:128 sc0 sc1\n\t" \
        "global_load_dwordx4 %3, %16, off offset:192 sc0 sc1\n\t" \
        "global_load_dwordx4 %4, %16, off offset:256 sc0 sc1\n\t" \
        "global_load_dwordx4 %5, %16, off offset:320 sc0 sc1\n\t" \
        "global_load_dwordx4 %6, %16, off offset:384 sc0 sc1\n\t" \
        "global_load_dwordx4 %7, %16, off offset:448 sc0 sc1\n\t" \
        "global_load_dwordx4 %8, %16, off offset:512 sc0 sc1\n\t" \
        "global_load_dwordx4 %9, %16, off offset:576 sc0 sc1\n\t" \
        "global_load_dwordx4 %10, %16, off offset:640 sc0 sc1\n\t" \
        "global_load_dwordx4 %11, %16, off offset:704 sc0 sc1\n\t" \
        "global_load_dwordx4 %12, %16, off offset:768 sc0 sc1\n\t" \
        "global_load_dwordx4 %13, %16, off offset:832 sc0 sc1\n\t" \
        "global_load_dwordx4 %14, %16, off offset:896 sc0 sc1\n\t" \
        "global_load_dwordx4 %15, %16, off offset:960 sc0 sc1\n\t" \
        "s_waitcnt vmcnt(0)" \
        : "=&v"(d[0]), "=&v"(d[1]), "=&v"(d[2]), "=&v"(d[3]), \
          "=&v"(d[4]), "=&v"(d[5]), "=&v"(d[6]), "=&v"(d[7]), \
          "=&v"(d[8]), "=&v"(d[9]), "=&v"(d[10]), "=&v"(d[11]), \
          "=&v"(d[12]), "=&v"(d[13]), "=&v"(d[14]), "=&v"(d[15]) \
        : "v"(base) : "memory")

#define MFMA16(a, b, c) __builtin_amdgcn_mfma_f32_16x16x32_f16(a, b, c, 0, 0, 0)

// arrive: drain my sc stores, block-sync, thread0 publishes monotone tag
#define ARRIVE(flagsp, tagv) do { \
    asm volatile("s_waitcnt vmcnt(0)" ::: "memory"); \
    __syncthreads(); \
    if (tid == 0) { int _tg = (tagv); \
        asm volatile("global_store_dword %0, %1, off sc0 sc1" :: "v"((flagsp) + cb), "v"(_tg) : "memory"); } \
} while (0)

// wait: thread0 polls all 8 flags >= tag
#define WAITF(flagsp, tagv) do { \
    if (tid == 0) { \
        for (;;) { \
            int4 _a, _b; \
            asm volatile("global_load_dwordx4 %0, %2, off sc0 sc1\n\t" \
                         "global_load_dwordx4 %1, %2, off offset:16 sc0 sc1\n\t" \
                         "s_waitcnt vmcnt(0)" \
                         : "=&v"(_a), "=&v"(_b) : "v"(flagsp) : "memory"); \
            int _m0 = min(min(_a.x, _a.y), min(_a.z, _a.w)); \
            int _m1 = min(min(_b.x, _b.y), min(_b.z, _b.w)); \
            if (min(_m0, _m1) >= (tagv)) break; \
        } \
    } \
    __syncthreads(); \
    __builtin_amdgcn_sched_barrier(0); \
} while (0)

#define PHASE1(S, TAGA) do { \
    f32x4 a0 = {0.f,0.f,0.f,0.f}, a1 = {0.f,0.f,0.f,0.f}; \
    a0 = MFMA16(xf##S[0], w1f[0], a0);  a1 = MFMA16(xf##S[1], w1f[1], a1); \
    a0 = MFMA16(xf##S[2], w1f[2], a0);  a1 = MFMA16(xf##S[3], w1f[3], a1); \
    a0 = MFMA16(hfrag##S[0], w1f[4], a0);  a1 = MFMA16(hfrag##S[1], w1f[5], a1); \
    a0 = MFMA16(hfrag##S[2], w1f[6], a0);  a1 = MFMA16(hfrag##S[3], w1f[7], a1); \
    a0 = MFMA16(hfrag##S[4], w1f[8], a0);  a1 = MFMA16(hfrag##S[5], w1f[9], a1); \
    a0 = MFMA16(hfrag##S[6], w1f[10], a0); a1 = MFMA16(hfrag##S[7], w1f[11], a1); \
    _Pragma("unroll") \
    for (int i = 0; i < 4; ++i) \
        xpose##S[lg * 4 + i][w * 16 + lc] = (_Float16)lecun_act(a0[i] + a1[i] + b1c); \
    __syncthreads(); \
    if (tid < 128) { int row = tid >> 3, seg = tid & 7; \
        stg16_sys(z1g##S + row * Uu + cb * 64 + seg * 8, *(const f16x8*)&xpose##S[row][seg * 8]); } \
    ARRIVE(flags##S, TAGA); \
} while (0)

#define PHASE2(S, TAGW, TAGA) do { \
    WAITF(flags##S, TAGW); \
    f16x8 zf[16]; \
    LD16_FRAGS(zf, z1g##S + lc * Uu + lg * 8); \
    f32x4 a0 = {0.f,0.f,0.f,0.f}, a1 = {0.f,0.f,0.f,0.f}; \
    _Pragma("unroll") \
    for (int kt = 0; kt < 16; ++kt) { \
        if (kt & 1) a1 = MFMA16(zf[kt], w2f[kt], a1); \
        else        a0 = MFMA16(zf[kt], w2f[kt], a0); \
    } \
    _Pragma("unroll") \
    for (int i = 0; i < 4; ++i) \
        xpose##S[lg * 4 + i][w * 16 + lc] = (_Float16)lecun_act(a0[i] + a1[i] + b2c); \
    __syncthreads(); \
    if (tid < 128) { int row = tid >> 3, seg = tid & 7; \
        stg16_sys(z2g##S + row * Uu + cb * 64 + seg * 8, *(const f16x8*)&xpose##S[row][seg * 8]); } \
    ARRIVE(flags##S, TAGA); \
} while (0)

#define PHASE3(S, TAGW, TAGA, T) do { \
    WAITF(flags##S, TAGW); \
    f16x8 zf[16]; \
    LD16_FRAGS(zf, z2g##S + lc * Uu + lg * 8); \
    f32x4 a0 = {0.f,0.f,0.f,0.f}, a1 = {0.f,0.f,0.f,0.f}; \
    _Pragma("unroll") \
    for (int kt = 0; kt < 16; ++kt) { \
        a0 = MFMA16(zf[kt], whf[kt], a0); \
        a1 = MFMA16(zf[kt], whf[16 + kt], a1); \
    } \
    if (isOdd) { \
        _Pragma("unroll") \
        for (int i = 0; i < 4; ++i) { \
            taL##S[w >> 1][0][lg * 4 + i][lc] = a0[i] + btac; \
            taL##S[w >> 1][1][lg * 4 + i][lc] = a1[i] + btbc; \
        } \
    } \
    __syncthreads(); \
    if (!isOdd) { \
        _Pragma("unroll") \
        for (int i = 0; i < 4; ++i) { \
            int row = lg * 4 + i; \
            float tsv = ts[(size_t)(r0##S + row) * Tt + (T)]; \
            float ff1 = fast_tanh(a0[i] + bf1c); \
            float ff2 = fast_tanh(a1[i] + bf2c); \
            float ta = taL##S[w >> 1][0][row][lc]; \
            float tb = taL##S[w >> 1][1][row][lc]; \
            float s = fast_sigmoid(ta * (tsv * (1.0f / 256.0f)) + tb); \
            xpose##S[row][(w >> 1) * 16 + lc] = (_Float16)(ff1 + s * (ff2 - ff1)); \
        } \
    } \
    __syncthreads(); \
    if (tid < 64) { int row = tid >> 2, seg = tid & 3; \
        stg16_sys(hg##S + row * Hh + cb * 32 + seg * 8, *(const f16x8*)&xpose##S[row][seg * 8]); } \
    ARRIVE(flags##S, TAGA); \
} while (0)

#define PHASE4(S, TAGW, T) do { \
    WAITF(flags##S, TAGW); \
    LD8_FRAGS(hfrag##S, hg##S + lc * Hh + lg * 8); \
    if ((T) + 1 < Tt) { \
        const float* xr = x + ((size_t)(r0##S + lc) * Tt + ((T) + 1)) * Ff + lg * 8; \
        _Pragma("unroll") \
        for (int kt = 0; kt < 4; ++kt) { \
            f32x4 xa = *(const f32x4*)(xr + kt * 32); \
            f32x4 xb = *(const f32x4*)(xr + kt * 32 + 4); \
            f16x8 af; \
            _Pragma("unroll") \
            for (int q = 0; q < 4; ++q) { af[q] = (_Float16)xa[q]; af[4 + q] = (_Float16)xb[q]; } \
            xf##S[kt] = af; \
        } \
    } \
    if (w == 0) { \
        f32x4 a0 = {0.f,0.f,0.f,0.f}, a1 = {0.f,0.f,0.f,0.f}; \
        a0 = MFMA16(hfrag##S[0], wof[0], a0); a1 = MFMA16(hfrag##S[1], wof[1], a1); \
        a0 = MFMA16(hfrag##S[2], wof[2], a0); a1 = MFMA16(hfrag##S[3], wof[3], a1); \
        a0 = MFMA16(hfrag##S[4], wof[4], a0); a1 = MFMA16(hfrag##S[5], wof[5], a1); \
        a0 = MFMA16(hfrag##S[6], wof[6], a0); a1 = MFMA16(hfrag##S[7], wof[7], a1); \
        _Pragma("unroll") \
        for (int i = 0; i < 4; ++i) \
            out[((size_t)(r0##S + lg * 4 + i) * Tt + (T)) * OUTo + colO] = a0[i] + a1[i] + boc; \
    } \
} while (0)

__global__ __launch_bounds__(256, 1)
void cfc_main(const float* __restrict__ x, const float* __restrict__ ts,
              const float* __restrict__ b1g, const float* __restrict__ b2g,
              const float* __restrict__ bff1g, const float* __restrict__ bff2g,
              const float* __restrict__ btag, const float* __restrict__ btbg,
              const float* __restrict__ boutg,
              const _Float16* __restrict__ wsf,
              char* __restrict__ actbase, int* __restrict__ cntbase,
              float* __restrict__ out)
{
    __shared__ float taLA[2][2][16][17], taLB[2][2][16][17];
    __shared__ __align__(16) _Float16 xposeA[16][72], xposeB[16][72];

    const int tid = threadIdx.x;
    const int l = tid & 63, w = tid >> 6;         // 4 waves
    const int lc = l & 15, lg = l >> 4;
    const int pair = blockIdx.x & 15;             // 16 cluster-pairs
    const int cb = blockIdx.x >> 4;               // 8 blocks per cluster
    const int clA = pair * 2, clB = pair * 2 + 1;
    const int r0A = clA * 16, r0B = clB * 16;

    // ---- weight fragments -> registers, pinned (shared by both groups) ----
    const _Float16* wb = wsf + ((size_t)(cb * 4 + w) * NSLOT) * 512 + l * 8;
    f16x8 w1f[12], w2f[16], whf[32], wof[8];
#pragma unroll
    for (int s = 0; s < 12; ++s) w1f[s] = *(const f16x8*)(wb + s * 512);
#pragma unroll
    for (int s = 0; s < 16; ++s) w2f[s] = *(const f16x8*)(wb + (12 + s) * 512);
#pragma unroll
    for (int s = 0; s < 32; ++s) whf[s] = *(const f16x8*)(wb + (28 + s) * 512);
#pragma unroll
    for (int s = 0; s < 8; ++s)  wof[s] = *(const f16x8*)(wb + (60 + s) * 512);
#pragma unroll
    for (int s = 0; s < 12; ++s) asm volatile("" : "+v"(w1f[s]));
#pragma unroll
    for (int s = 0; s < 16; ++s) asm volatile("" : "+v"(w2f[s]));
#pragma unroll
    for (int s = 0; s < 32; ++s) asm volatile("" : "+v"(whf[s]));
#pragma unroll
    for (int s = 0; s < 8; ++s)  asm volatile("" : "+v"(wof[s]));

    // ---- per-lane biases (column-slice -> identical for both groups) ----
    const int colU = cb * 64 + w * 16 + lc;
    const int hcol = cb * 32 + (w >> 1) * 16 + lc;
    const int colO = cb * 16 + lc;
    const float b1c = b1g[colU], b2c = b2g[colU];
    const float bf1c = bff1g[hcol], bf2c = bff2g[hcol];
    const float btac = btag[hcol], btbc = btbg[hcol];
    const float boc = boutg[colO];

    char* actA = actbase + (size_t)clA * ACT_STRIDE;
    char* actB = actbase + (size_t)clB * ACT_STRIDE;
    _Float16* z1gA = (_Float16*)actA;
    _Float16* z2gA = (_Float16*)(actA + 16384);
    _Float16* hgA  = (_Float16*)(actA + 32768);
    _Float16* z1gB = (_Float16*)actB;
    _Float16* z2gB = (_Float16*)(actB + 16384);
    _Float16* hgB  = (_Float16*)(actB + 32768);
    int* flagsA = cntbase + clA * 8;
    int* flagsB = cntbase + clB * 8;

    f16x8 hfragA[8], hfragB[8];
#pragma unroll
    for (int s = 0; s < 8; ++s) { hfragA[s] = f16x8{0,0,0,0,0,0,0,0}; hfragB[s] = f16x8{0,0,0,0,0,0,0,0}; }

    f16x8 xfA[4], xfB[4];
    {
        const float* xrA = x + ((size_t)(r0A + lc) * Tt + 0) * Ff + lg * 8;
        const float* xrB = x + ((size_t)(r0B + lc) * Tt + 0) * Ff + lg * 8;
#pragma unroll
        for (int kt = 0; kt < 4; ++kt) {
            f32x4 xa = *(const f32x4*)(xrA + kt * 32);
            f32x4 xb = *(const f32x4*)(xrA + kt * 32 + 4);
            f16x8 af;
#pragma unroll
            for (int q = 0; q < 4; ++q) { af[q] = (_Float16)xa[q]; af[4 + q] = (_Float16)xb[q]; }
            xfA[kt] = af;
            xa = *(const f32x4*)(xrB + kt * 32);
            xb = *(const f32x4*)(xrB + kt * 32 + 4);
#pragma unroll
            for (int q = 0; q < 4; ++q) { af[q] = (_Float16)xa[q]; af[4 + q] = (_Float16)xb[q]; }
            xfB[kt] = af;
        }
    }

    const int isOdd = w & 1;

    for (int t = 0; t < Tt; ++t) {
        PHASE1(A, t * 3 + 1);
        PHASE1(B, t * 3 + 1);
        PHASE2(A, t * 3 + 1, t * 3 + 2);
        PHASE2(B, t * 3 + 1, t * 3 + 2);
        PHASE3(A, t * 3 + 2, t * 3 + 3, t);
        PHASE3(B, t * 3 + 2, t * 3 + 3, t);
        PHASE4(A, t * 3 + 3, t);
        PHASE4(B, t * 3 + 3, t);
    }
}

extern "C" void kernel_launch(void* const* d_in, const int* in_sizes, int n_in,
                              void* d_out, int out_size, void* d_ws, size_t ws_size,
                              hipStream_t stream) {
    const float* x    = (const float*)d_in[0];
    const float* ts   = (const float*)d_in[1];
    const float* W1   = (const float*)d_in[2];
    const float* b1   = (const float*)d_in[3];
    const float* W2   = (const float*)d_in[4];
    const float* b2   = (const float*)d_in[5];
    const float* Wff1 = (const float*)d_in[6];
    const float* bff1 = (const float*)d_in[7];
    const float* Wff2 = (const float*)d_in[8];
    const float* bff2 = (const float*)d_in[9];
    const float* Wta  = (const float*)d_in[10];
    const float* bta  = (const float*)d_in[11];
    const float* Wtb  = (const float*)d_in[12];
    const float* btb  = (const float*)d_in[13];
    const float* Wout = (const float*)d_in[14];
    const float* bout = (const float*)d_in[15];
    float* out = (float*)d_out;

    _Float16* wf = (_Float16*)d_ws;
    char* act = (char*)d_ws + ACT_OFF;
    int* cnt = (int*)((char*)d_ws + CNT_OFF);

    hipMemsetAsync(cnt, 0, CNT_BYTES, stream);
    prep_weights<<<(NFRAG * 512) / 256, 256, 0, stream>>>(W1, W2, Wff1, Wff2, Wta, Wtb, Wout, wf);
    cfc_main<<<NPAIR * CBLK, 256, 0, stream>>>(x, ts, b1, b2, bff1, bff2, bta, btb, bout,
                                               wf, act, cnt, out);
}

// Round 8
// 3867.170 us; speedup vs baseline: 1.4294x; 1.4294x over previous
//
#include <hip/hip_runtime.h>

typedef _Float16 f16x8 __attribute__((ext_vector_type(8)));
typedef _Float16 f16x4 __attribute__((ext_vector_type(4)));
typedef float    f32x4 __attribute__((ext_vector_type(4)));

#define DEVINL __device__ __forceinline__

namespace {
constexpr int Tt = 256, Ff = 128, Hh = 256, Uu = 512, OUTo = 128;
constexpr int NCLUST = 32;               // 512 / 16 row-groups
constexpr int CBLK = 8;                  // blocks per cluster
constexpr int NSLOT = 68;                // frags per (cb, wave): 12 W1 + 16 W2 + 32 heads + 8 Wout
constexpr int NFRAG = CBLK * 4 * NSLOT;  // 2176 fragments
constexpr size_t WFRAG_BYTES = (size_t)NFRAG * 1024;
constexpr size_t ACT_OFF = WFRAG_BYTES;
constexpr size_t ACT_STRIDE = 40960;     // z1 16K | z2 16K | h 8K (+pad)
constexpr size_t CNT_OFF = ACT_OFF + (size_t)NCLUST * ACT_STRIDE;
constexpr size_t CNT_BYTES = (size_t)NCLUST * 32 * 4;   // 32 per-wave flags per cluster
}

// ---- weight prep: f32 row-major -> per-(cb,wave) fp16 MFMA fragment banks ----
__global__ void prep_weights(const float* __restrict__ W1, const float* __restrict__ W2,
                             const float* __restrict__ Wff1, const float* __restrict__ Wff2,
                             const float* __restrict__ Wta, const float* __restrict__ Wtb,
                             const float* __restrict__ Wout, _Float16* __restrict__ ws)
{
    int o = blockIdx.x * blockDim.x + threadIdx.x;
    if (o >= NFRAG * 512) return;
    int j = o & 7, l = (o >> 3) & 63, r = o >> 9;
    int slot = r % NSLOT, bw = r / NSLOT;
    int w = bw & 3, cb = bw >> 2;
    int k_in = ((l >> 4) << 3) + j, lc = l & 15;
    float v;
    if (slot < 12) {
        int kt = slot;
        v = W1[(kt * 32 + k_in) * Uu + cb * 64 + w * 16 + lc];
    } else if (slot < 28) {
        int kt = slot - 12;
        v = W2[(kt * 32 + k_in) * Uu + cb * 64 + w * 16 + lc];
    } else if (slot < 60) {
        int s = slot - 28, hpL = s >> 4, kt = s & 15;
        int head = (w & 1) * 2 + hpL;
        const float* W = (head == 0) ? Wff1 : (head == 1) ? Wff2 : (head == 2) ? Wta : Wtb;
        v = W[(kt * 32 + k_in) * Hh + cb * 32 + (w >> 1) * 16 + lc];
    } else {
        int kt = slot - 60;
        v = Wout[(kt * 32 + k_in) * OUTo + cb * 16 + lc];
    }
    ws[o] = (_Float16)v;
}

DEVINL float fast_tanh(float v) {
    float e = __expf(2.0f * v);
    return 1.0f - 2.0f / (e + 1.0f);
}
DEVINL float fast_sigmoid(float v) { return 1.0f / (1.0f + __expf(-v)); }
DEVINL float lecun_act(float v)    { return 1.7159f * fast_tanh(0.666f * v); }

// ---- MALL-coherent (sc0 sc1) accessors ----
DEVINL void stg8_sys(_Float16* p, f16x4 v) {
    asm volatile("global_store_dwordx2 %0, %1, off sc0 sc1" :: "v"(p), "v"(v) : "memory");
}

#define LD8_FRAGS(d, base) \
    asm volatile( \
        "global_load_dwordx4 %0, %8, off sc0 sc1\n\t" \
        "global_load_dwordx4 %1, %8, off offset:64 sc0 sc1\n\t" \
        "global_load_dwordx4 %2, %8, off offset:128 sc0 sc1\n\t" \
        "global_load_dwordx4 %3, %8, off offset:192 sc0 sc1\n\t" \
        "global_load_dwordx4 %4, %8, off offset:256 sc0 sc1\n\t" \
        "global_load_dwordx4 %5, %8, off offset:320 sc0 sc1\n\t" \
        "global_load_dwordx4 %6, %8, off offset:384 sc0 sc1\n\t" \
        "global_load_dwordx4 %7, %8, off offset:448 sc0 sc1\n\t" \
        "s_waitcnt vmcnt(0)" \
        : "=&v"(d[0]), "=&v"(d[1]), "=&v"(d[2]), "=&v"(d[3]), \
          "=&v"(d[4]), "=&v"(d[5]), "=&v"(d[6]), "=&v"(d[7]) \
        : "v"(base) : "memory")

#define LD16_FRAGS(d, base) \
    asm volatile( \
        "global_load_dwordx4 %0, %16, off sc0 sc1\n\t" \
        "global_load_dwordx4 %1, %16, off offset:64 sc0 sc1\n\t" \
        "global_load_dwordx4 %2, %16, off offset:128 sc0 sc1\n\t" \
        "global_load_dwordx4 %3, %16, off offset:192 sc0 sc1\n\t" \
        "global_load_dwordx4 %4, %16, off offset:256 sc0 sc1\n\t" \
        "global_load_dwordx4 %5, %16, off offset:320 sc0 sc1\n\t" \
        "global_load_dwordx4 %6, %16, off offset:384 sc0 sc1\n\t" \
        "global_load_dwordx4 %7, %16, off offset:448 sc0 sc1\n\t" \
        "global_load_dwordx4 %8, %16, off offset:512 sc0 sc1\n\t" \
        "global_load_dwordx4 %9, %16, off offset:576 sc0 sc1\n\t" \
        "global_load_dwordx4 %10, %16, off offset:640 sc0 sc1\n\t" \
        "global_load_dwordx4 %11, %16, off offset:704 sc0 sc1\n\t" \
        "global_load_dwordx4 %12, %16, off offset:768 sc0 sc1\n\t" \
        "global_load_dwordx4 %13, %16, off offset:832 sc0 sc1\n\t" \
        "global_load_dwordx4 %14, %16, off offset:896 sc0 sc1\n\t" \
        "global_load_dwordx4 %15, %16, off offset:960 sc0 sc1\n\t" \
        "s_waitcnt vmcnt(0)" \
        : "=&v"(d[0]), "=&v"(d[1]), "=&v"(d[2]), "=&v"(d[3]), \
          "=&v"(d[4]), "=&v"(d[5]), "=&v"(d[6]), "=&v"(d[7]), \
          "=&v"(d[8]), "=&v"(d[9]), "=&v"(d[10]), "=&v"(d[11]), \
          "=&v"(d[12]), "=&v"(d[13]), "=&v"(d[14]), "=&v"(d[15]) \
        : "v"(base) : "memory")

#define MFMA16(a, b, c) __builtin_amdgcn_mfma_f32_16x16x32_f16(a, b, c, 0, 0, 0)

// per-wave arrive: drain this wave's stores, lane0 publishes monotone tag
DEVINL void arrive(int* flags, int fidx, int tag, int l) {
    asm volatile("s_waitcnt vmcnt(0)" ::: "memory");
    if (l == 0)
        asm volatile("global_store_dword %0, %1, off sc0 sc1" :: "v"(flags + fidx), "v"(tag) : "memory");
}

// per-wave wait: all 64 lanes poll the 32 flags (coalesced), ballot on >= tag
DEVINL void waitf(const int* flags, int tag, int l) {
    const int* p = flags + (l & 31);
    for (;;) {
        int v;
        asm volatile("global_load_dword %0, %1, off sc0 sc1\n\t"
                     "s_waitcnt vmcnt(0)"
                     : "=v"(v) : "v"(p) : "memory");
        if (__all(v >= tag)) break;
    }
    __builtin_amdgcn_sched_barrier(0);
}

__global__ __launch_bounds__(256, 1)
void cfc_main(const float* __restrict__ x, const float* __restrict__ ts,
              const float* __restrict__ b1g, const float* __restrict__ b2g,
              const float* __restrict__ bff1g, const float* __restrict__ bff2g,
              const float* __restrict__ btag, const float* __restrict__ btbg,
              const float* __restrict__ boutg,
              const _Float16* __restrict__ wsf,
              char* __restrict__ actbase, int* __restrict__ cntbase,
              float* __restrict__ out)
{
    __shared__ float taL[2][2][2][16][17];            // [t&1][hcol-tile][ta/tb][row][col]
    __shared__ __align__(8) _Float16 xp[4][16][20];   // per-wave transpose tiles

    const int tid = threadIdx.x;
    const int l = tid & 63, w = tid >> 6;             // 4 waves
    const int lc = l & 15, lg = l >> 4;
    const int xr = l >> 2, xs = l & 3;                // xpose readback row/seg
    const int cluster = blockIdx.x & 31;
    const int cb = blockIdx.x >> 5;
    const int r0 = cluster * 16;

    // ---- weight fragments -> registers ----
    const _Float16* wb = wsf + ((size_t)(cb * 4 + w) * NSLOT) * 512 + l * 8;
    f16x8 w1f[12], w2f[16], whf[32], wof[8];
#pragma unroll
    for (int s = 0; s < 12; ++s) w1f[s] = *(const f16x8*)(wb + s * 512);
#pragma unroll
    for (int s = 0; s < 16; ++s) w2f[s] = *(const f16x8*)(wb + (12 + s) * 512);
#pragma unroll
    for (int s = 0; s < 32; ++s) whf[s] = *(const f16x8*)(wb + (28 + s) * 512);
#pragma unroll
    for (int s = 0; s < 8; ++s)  wof[s] = *(const f16x8*)(wb + (60 + s) * 512);

    // ---- per-lane biases ----
    const int colU = cb * 64 + w * 16 + lc;
    const int hcol = cb * 32 + (w >> 1) * 16 + lc;
    const int colO = cb * 16 + lc;
    const float b1c = b1g[colU], b2c = b2g[colU];
    const float bf1c = bff1g[hcol], bf2c = bff2g[hcol];
    const float btac = btag[hcol], btbc = btbg[hcol];
    const float boc = boutg[colO];

    char* act = actbase + (size_t)cluster * ACT_STRIDE;
    _Float16* z1g = (_Float16*)act;               // [16][512]
    _Float16* z2g = (_Float16*)(act + 16384);     // [16][512]
    _Float16* hg  = (_Float16*)(act + 32768);     // [16][256]
    int* flags = cntbase + cluster * 32;
    const int fidx = cb * 4 + w;

    f16x8 hfrag[8];
#pragma unroll
    for (int s = 0; s < 8; ++s) hfrag[s] = f16x8{0,0,0,0,0,0,0,0};

    f16x8 xf[4];
    {
        const float* xr_ = x + ((size_t)(r0 + lc) * Tt + 0) * Ff + lg * 8;
#pragma unroll
        for (int kt = 0; kt < 4; ++kt) {
            f32x4 xa = *(const f32x4*)(xr_ + kt * 32);
            f32x4 xb = *(const f32x4*)(xr_ + kt * 32 + 4);
            f16x8 af;
#pragma unroll
            for (int q = 0; q < 4; ++q) { af[q] = (_Float16)xa[q]; af[4 + q] = (_Float16)xb[q]; }
            xf[kt] = af;
        }
    }

    for (int t = 0; t < Tt; ++t) {
        // ---- pin weights resident across the iteration (defeats remat-by-reload) ----
#pragma unroll
        for (int s = 0; s < 12; ++s) asm volatile("" : "+v"(w1f[s]));
#pragma unroll
        for (int s = 0; s < 16; ++s) asm volatile("" : "+v"(w2f[s]));
#pragma unroll
        for (int s = 0; s < 32; ++s) asm volatile("" : "+v"(whf[s]));
#pragma unroll
        for (int s = 0; s < 8; ++s)  asm volatile("" : "+v"(wof[s]));

        // ---------- P1: z1 = lecun([x|h] @ W1 + b1) ----------
        {
            f32x4 a0 = {0.f,0.f,0.f,0.f}, a1 = {0.f,0.f,0.f,0.f};
            a0 = MFMA16(xf[0], w1f[0], a0);  a1 = MFMA16(xf[1], w1f[1], a1);
            a0 = MFMA16(xf[2], w1f[2], a0);  a1 = MFMA16(xf[3], w1f[3], a1);
            a0 = MFMA16(hfrag[0], w1f[4], a0);  a1 = MFMA16(hfrag[1], w1f[5], a1);
            a0 = MFMA16(hfrag[2], w1f[6], a0);  a1 = MFMA16(hfrag[3], w1f[7], a1);
            a0 = MFMA16(hfrag[4], w1f[8], a0);  a1 = MFMA16(hfrag[5], w1f[9], a1);
            a0 = MFMA16(hfrag[6], w1f[10], a0); a1 = MFMA16(hfrag[7], w1f[11], a1);
#pragma unroll
            for (int i = 0; i < 4; ++i)
                xp[w][lg * 4 + i][lc] = (_Float16)lecun_act(a0[i] + a1[i] + b1c);
            asm volatile("s_waitcnt lgkmcnt(0)" ::: "memory");
            __builtin_amdgcn_sched_barrier(0);
            f16x4 v = *(const f16x4*)&xp[w][xr][xs * 4];
            stg8_sys(z1g + xr * Uu + cb * 64 + w * 16 + xs * 4, v);
        }
        arrive(flags, fidx, 3 * t + 1, l);

        // ---------- P2: z2 = lecun(z1 @ W2 + b2) ----------
        waitf(flags, 3 * t + 1, l);
        {
            f16x8 zf[16];
            LD16_FRAGS(zf, z1g + lc * Uu + lg * 8);
            f32x4 a0 = {0.f,0.f,0.f,0.f}, a1 = {0.f,0.f,0.f,0.f};
#pragma unroll
            for (int kt = 0; kt < 16; ++kt) {
                if (kt & 1) a1 = MFMA16(zf[kt], w2f[kt], a1);
                else        a0 = MFMA16(zf[kt], w2f[kt], a0);
            }
#pragma unroll
            for (int i = 0; i < 4; ++i)
                xp[w][lg * 4 + i][lc] = (_Float16)lecun_act(a0[i] + a1[i] + b2c);
            asm volatile("s_waitcnt lgkmcnt(0)" ::: "memory");
            __builtin_amdgcn_sched_barrier(0);
            f16x4 v = *(const f16x4*)&xp[w][xr][xs * 4];
            stg8_sys(z2g + xr * Uu + cb * 64 + w * 16 + xs * 4, v);
        }
        arrive(flags, fidx, 3 * t + 2, l);

        // ---------- P3: heads + gate -> h(t) ----------
        waitf(flags, 3 * t + 2, l);
        {
            f16x8 zf[16];
            LD16_FRAGS(zf, z2g + lc * Uu + lg * 8);
            f32x4 h0 = {0.f,0.f,0.f,0.f}, h1 = {0.f,0.f,0.f,0.f};
#pragma unroll
            for (int kt = 0; kt < 16; ++kt) {
                h0 = MFMA16(zf[kt], whf[kt], h0);
                h1 = MFMA16(zf[kt], whf[16 + kt], h1);
            }
            if (w & 1) {          // heads 2,3 = ta, tb -> LDS (double-buffered)
#pragma unroll
                for (int i = 0; i < 4; ++i) {
                    taL[t & 1][w >> 1][0][lg * 4 + i][lc] = h0[i] + btac;
                    taL[t & 1][w >> 1][1][lg * 4 + i][lc] = h1[i] + btbc;
                }
            }
            __syncthreads();
            if (!(w & 1)) {       // heads 0,1 = ff1, ff2 + gate + h store
#pragma unroll
                for (int i = 0; i < 4; ++i) {
                    int row = lg * 4 + i;
                    float tsv = ts[(size_t)(r0 + row) * Tt + t];
                    float ff1 = fast_tanh(h0[i] + bf1c);
                    float ff2 = fast_tanh(h1[i] + bf2c);
                    float ta = taL[t & 1][w >> 1][0][row][lc];
                    float tb = taL[t & 1][w >> 1][1][row][lc];
                    float s = fast_sigmoid(ta * (tsv * (1.0f / 256.0f)) + tb);
                    xp[w][row][lc] = (_Float16)(ff1 + s * (ff2 - ff1));
                }
                asm volatile("s_waitcnt lgkmcnt(0)" ::: "memory");
                __builtin_amdgcn_sched_barrier(0);
                f16x4 v = *(const f16x4*)&xp[w][xr][xs * 4];
                stg8_sys(hg + xr * Hh + cb * 32 + (w >> 1) * 16 + xs * 4, v);
            }
        }
        arrive(flags, fidx, 3 * t + 3, l);

        // ---------- P4: h gather; x(t+1) prefetch; out(t) ----------
        waitf(flags, 3 * t + 3, l);
        {
            f32x4 xa[4], xb[4];
            if (t + 1 < Tt) {
                const float* xr_ = x + ((size_t)(r0 + lc) * Tt + (t + 1)) * Ff + lg * 8;
#pragma unroll
                for (int kt = 0; kt < 4; ++kt) {
                    xa[kt] = *(const f32x4*)(xr_ + kt * 32);
                    xb[kt] = *(const f32x4*)(xr_ + kt * 32 + 4);
                }
            }
            LD8_FRAGS(hfrag, hg + lc * Hh + lg * 8);
            if (t + 1 < Tt) {
#pragma unroll
                for (int kt = 0; kt < 4; ++kt) {
                    f16x8 af;
#pragma unroll
                    for (int q = 0; q < 4; ++q) { af[q] = (_Float16)xa[kt][q]; af[4 + q] = (_Float16)xb[kt][q]; }
                    xf[kt] = af;
                }
            }
            if (w == 0) {
                f32x4 a0 = {0.f,0.f,0.f,0.f}, a1 = {0.f,0.f,0.f,0.f};
                a0 = MFMA16(hfrag[0], wof[0], a0); a1 = MFMA16(hfrag[1], wof[1], a1);
                a0 = MFMA16(hfrag[2], wof[2], a0); a1 = MFMA16(hfrag[3], wof[3], a1);
                a0 = MFMA16(hfrag[4], wof[4], a0); a1 = MFMA16(hfrag[5], wof[5], a1);
                a0 = MFMA16(hfrag[6], wof[6], a0); a1 = MFMA16(hfrag[7], wof[7], a1);
#pragma unroll
                for (int i = 0; i < 4; ++i)
                    out[((size_t)(r0 + lg * 4 + i) * Tt + t) * OUTo + colO] = a0[i] + a1[i] + boc;
            }
        }
    }
}

extern "C" void kernel_launch(void* const* d_in, const int* in_sizes, int n_in,
                              void* d_out, int out_size, void* d_ws, size_t ws_size,
                              hipStream_t stream) {
    const float* x    = (const float*)d_in[0];
    const float* ts   = (const float*)d_in[1];
    const float* W1   = (const float*)d_in[2];
    const float* b1   = (const float*)d_in[3];
    const float* W2   = (const float*)d_in[4];
    const float* b2   = (const float*)d_in[5];
    const float* Wff1 = (const float*)d_in[6];
    const float* bff1 = (const float*)d_in[7];
    const float* Wff2 = (const float*)d_in[8];
    const float* bff2 = (const float*)d_in[9];
    const float* Wta  = (const float*)d_in[10];
    const float* bta  = (const float*)d_in[11];
    const float* Wtb  = (const float*)d_in[12];
    const float* btb  = (const float*)d_in[13];
    const float* Wout = (const float*)d_in[14];
    const float* bout = (const float*)d_in[15];
    float* out = (float*)d_out;

    _Float16* wf = (_Float16*)d_ws;
    char* act = (char*)d_ws + ACT_OFF;
    int* cnt = (int*)((char*)d_ws + CNT_OFF);

    hipMemsetAsync(cnt, 0, CNT_BYTES, stream);
    prep_weights<<<(NFRAG * 512) / 256, 256, 0, stream>>>(W1, W2, Wff1, Wff2, Wta, Wtb, Wout, wf);
    cfc_main<<<NCLUST * CBLK, 256, 0, stream>>>(x, ts, b1, b2, bff1, bff2, bta, btb, bout,
                                                wf, act, cnt, out);
}